// Round 7
// baseline (514.843 us; speedup 1.0000x reference)
//
#include <hip/hip_runtime.h>
#include <hip/hip_bf16.h>

// MHA: B=4, S=2048, E=1024, H=16, D=64. f32 in/out, bf16 MFMA internally.
//
// Pipeline (all in d_ws, bf16 storage as ushort):
//   Xb   = bf16(X)                     [8192,1024]
//   W*t  = bf16(W*^T)                  [1024,1024] (N,K layout for B^T GEMM)
//   Q/K/Vb = Xb @ W*t + b*             [8192,1024]  (gemm_bt, bf16 out)
//   Ab   = flash_attention(Qb,Kb,Vb)   [8192,1024]  (merged-heads layout)
//          Ab aliases Xb (X dead after V projection)
//   out  = Ab @ Wot + bo               [8192,1024]  f32
//
// ws layout (ushort elems): Xb/Ab 8388608 | Wqt/Wkt/Wvt/Wot 1048576 ea |
//   Qb/Kb/Vb 8388608 ea  => 37,748,736 ushort = 72 MiB total.

#define S_LEN 2048
#define E_DIM 1024
#define H_NUM 16
#define D_DIM 64
#define M_ROWS 8192  // B*S

typedef float f32x4 __attribute__((ext_vector_type(4)));
typedef __bf16 b16x8 __attribute__((ext_vector_type(8)));
typedef unsigned short u16x8 __attribute__((ext_vector_type(8)));
typedef unsigned short u16x4 __attribute__((ext_vector_type(4)));

static __device__ __forceinline__ f32x4 mfma_bf16(b16x8 a, b16x8 b, f32x4 c) {
  return __builtin_amdgcn_mfma_f32_16x16x32_bf16(a, b, c, 0, 0, 0);
}

// f32 -> bf16 round-to-nearest-even
static __device__ __forceinline__ unsigned short f2b(float f) {
  union { float f; unsigned u; } v;
  v.f = f;
  unsigned r = v.u + 0x7fffu + ((v.u >> 16) & 1u);
  return (unsigned short)(r >> 16);
}

// async global->LDS, 16B per lane; lds dest must be wave-uniform base.
static __device__ __forceinline__ void async_ld16(const unsigned short* g,
                                                  const unsigned short* lds) {
  __builtin_amdgcn_global_load_lds(
      (const __attribute__((address_space(1))) void*)g,
      (__attribute__((address_space(3))) void*)lds, 16, 0, 0);
}

// ---------------------------------------------------------------- conversions

__global__ __launch_bounds__(256) void f32_to_bf16_kernel(
    const float* __restrict__ in, unsigned short* __restrict__ out, int n4) {
  const int i = blockIdx.x * 256 + threadIdx.x;
  if (i >= n4) return;
  const f32x4 v = *(const f32x4*)&in[(size_t)i * 4];
  u16x4 o;
  o.x = f2b(v.x); o.y = f2b(v.y); o.z = f2b(v.z); o.w = f2b(v.w);
  *(u16x4*)&out[(size_t)i * 4] = o;
}

// W [1024,1024] f32 row-major -> Wt [1024,1024] bf16 (Wt[n][k] = W[k][n])
__global__ __launch_bounds__(256) void transpose_w_kernel(
    const float* __restrict__ in, unsigned short* __restrict__ out) {
  __shared__ float tile[32][33];
  const int bx = blockIdx.x * 32, by = blockIdx.y * 32;
  const int tx = threadIdx.x & 31;
  const int ty = (threadIdx.x >> 5) * 4;  // 8 groups x 4 rows
#pragma unroll
  for (int i = 0; i < 4; ++i)
    tile[ty + i][tx] = in[(size_t)(by + ty + i) * 1024 + bx + tx];
  __syncthreads();
#pragma unroll
  for (int i = 0; i < 4; ++i)
    out[(size_t)(bx + ty + i) * 1024 + by + tx] = f2b(tile[tx][ty + i]);
}

// ------------------------------------------------------------------ GEMM B^T
// C[M,N] = A[M,K] @ Bt[N,K]^T + bias.  128x128 tile, BK=32, 4 waves (2x2),
// each wave 64x64 = 4x4 fragments of 16x16x32.  m97 structure.

template <int OUT_F32>
__global__ __launch_bounds__(256) void gemm_bt_kernel(
    const unsigned short* __restrict__ A, const unsigned short* __restrict__ Bt,
    const float* __restrict__ bias, void* __restrict__ Cout, int M, int N,
    int K) {
  __shared__ __align__(16) unsigned short As[128 * 32];
  __shared__ __align__(16) unsigned short Bs[128 * 32];

  const int tid = threadIdx.x;
  const int wid = tid >> 6;
  const int l = tid & 63;
  const int g = l >> 4;
  const int c = l & 15;
  const int wm = wid >> 1;
  const int wn = wid & 1;
  const int mbase = blockIdx.x * 128;
  const int nbase = blockIdx.y * 128;
  const int lrow = l >> 2;        // 0..15 within 16-row chunk
  const int scol = (l & 3) * 8;   // 0,8,16,24

  f32x4 acc[4][4];
#pragma unroll
  for (int i = 0; i < 4; ++i)
#pragma unroll
    for (int j = 0; j < 4; ++j) acc[i][j] = (f32x4){0.f, 0.f, 0.f, 0.f};

  for (int kt = 0; kt < K; kt += 32) {
#pragma unroll
    for (int i = 0; i < 2; ++i) {
      const int ci = wid * 2 + i;        // 0..7, wave-uniform
      const int row = ci * 16 + lrow;    // 0..127
      async_ld16(A + (size_t)(mbase + row) * K + kt + scol, As + ci * 512);
      async_ld16(Bt + (size_t)(nbase + row) * K + kt + scol, Bs + ci * 512);
    }
    __syncthreads();

    b16x8 af[4], bfr[4];
#pragma unroll
    for (int mi = 0; mi < 4; ++mi)
      af[mi] = *(const b16x8*)&As[(wm * 64 + mi * 16 + c) * 32 + g * 8];
#pragma unroll
    for (int ni = 0; ni < 4; ++ni)
      bfr[ni] = *(const b16x8*)&Bs[(wn * 64 + ni * 16 + c) * 32 + g * 8];
#pragma unroll
    for (int mi = 0; mi < 4; ++mi)
#pragma unroll
      for (int ni = 0; ni < 4; ++ni)
        acc[mi][ni] = mfma_bf16(af[mi], bfr[ni], acc[mi][ni]);
    __syncthreads();
  }

#pragma unroll
  for (int ni = 0; ni < 4; ++ni) {
    const int col = nbase + wn * 64 + ni * 16 + c;
    const float bv = bias[col];
#pragma unroll
    for (int mi = 0; mi < 4; ++mi)
#pragma unroll
      for (int r = 0; r < 4; ++r) {
        const int row = mbase + wm * 64 + mi * 16 + g * 4 + r;
        const float v = acc[mi][ni][r] + bv;
        if (OUT_F32)
          ((float*)Cout)[(size_t)row * N + col] = v;
        else
          ((unsigned short*)Cout)[(size_t)row * N + col] = f2b(v);
      }
  }
}

// ----------------------------------------------------------- flash attention
// Grid (S/128, B*H). 4 waves x 32 q-rows. KV tile = 64 rows.
// Q in registers; K in padded LDS; V transposed+swizzled in LDS;
// P round-trips per-wave padded LDS. Online softmax, scale 1/8.

__global__ __launch_bounds__(256) void attn_kernel(
    const unsigned short* __restrict__ Q, const unsigned short* __restrict__ K,
    const unsigned short* __restrict__ V, unsigned short* __restrict__ O) {
  __shared__ __align__(16) unsigned short Klds[64 * 72];
  __shared__ __align__(16) unsigned short Vt[64 * 72];    // [d][kv] swizzled
  __shared__ __align__(16) unsigned short Plds[4][32 * 72];

  const int tid = threadIdx.x;
  const int w = tid >> 6;
  const int l = tid & 63;
  const int g = l >> 4;
  const int c = l & 15;
  const int b = blockIdx.y >> 4;
  const int h = blockIdx.y & 15;
  const int qbase = blockIdx.x * 128;
  const size_t base_bh = (size_t)b * S_LEN * E_DIM + h * D_DIM;

  // Q fragments: rows qbase + w*32 + m*16 + c, k = kk*32 + g*8
  b16x8 qf[2][2];
#pragma unroll
  for (int m = 0; m < 2; ++m)
#pragma unroll
    for (int kk = 0; kk < 2; ++kk) {
      const int row = qbase + w * 32 + m * 16 + c;
      qf[m][kk] = *(const b16x8*)&Q[base_bh + (size_t)row * E_DIM + kk * 32 + g * 8];
    }

  f32x4 o[2][4];
#pragma unroll
  for (int m = 0; m < 2; ++m)
#pragma unroll
    for (int nd = 0; nd < 4; ++nd) o[m][nd] = (f32x4){0.f, 0.f, 0.f, 0.f};
  float mrun[2][4], lrun[2][4];
#pragma unroll
  for (int m = 0; m < 2; ++m)
#pragma unroll
    for (int r = 0; r < 4; ++r) { mrun[m][r] = -3.0e38f; lrun[m][r] = 0.f; }

  for (int t = 0; t < S_LEN / 64; ++t) {
    const int kvb = t * 64;
    // ---- stage K (row-major padded) and V (transposed, chunk-XOR swizzled)
#pragma unroll
    for (int i = 0; i < 2; ++i) {
      const int idx = tid + i * 256;      // 0..511
      const int row = idx >> 3;           // kv 0..63
      const int colc = (idx & 7) * 8;     // d chunk base
      const size_t gaddr = base_bh + (size_t)(kvb + row) * E_DIM + colc;
      const u16x8 k8 = *(const u16x8*)&K[gaddr];
      *(u16x8*)&Klds[row * 72 + colc] = k8;
      const u16x8 v8 = *(const u16x8*)&V[gaddr];
      const int dch = colc >> 3;
      const int chunk = ((row >> 3) ^ dch) & 7;  // swizzled kv-chunk slot
#pragma unroll
      for (int j = 0; j < 8; ++j)
        Vt[(colc + j) * 72 + chunk * 8 + (row & 7)] = v8[j];
    }
    __syncthreads();

    // ---- S = (Q K^T) * 0.125
    f32x4 sacc[2][4];
#pragma unroll
    for (int m = 0; m < 2; ++m)
#pragma unroll
      for (int n = 0; n < 4; ++n) sacc[m][n] = (f32x4){0.f, 0.f, 0.f, 0.f};
#pragma unroll
    for (int n = 0; n < 4; ++n)
#pragma unroll
      for (int kk = 0; kk < 2; ++kk) {
        const b16x8 kf = *(const b16x8*)&Klds[(n * 16 + c) * 72 + kk * 32 + g * 8];
#pragma unroll
        for (int m = 0; m < 2; ++m)
          sacc[m][n] = mfma_bf16(qf[m][kk], kf, sacc[m][n]);
      }

    // ---- online softmax (row = g*4+r+16m, cols across c lanes)
#pragma unroll
    for (int m = 0; m < 2; ++m)
#pragma unroll
      for (int r = 0; r < 4; ++r) {
        float mx = -3.0e38f;
#pragma unroll
        for (int n = 0; n < 4; ++n) {
          sacc[m][n][r] *= 0.125f;
          mx = fmaxf(mx, sacc[m][n][r]);
        }
        mx = fmaxf(mx, __shfl_xor(mx, 1));
        mx = fmaxf(mx, __shfl_xor(mx, 2));
        mx = fmaxf(mx, __shfl_xor(mx, 4));
        mx = fmaxf(mx, __shfl_xor(mx, 8));
        const float mnew = fmaxf(mrun[m][r], mx);
        const float corr = __expf(mrun[m][r] - mnew);
        mrun[m][r] = mnew;
        float ps = 0.f;
#pragma unroll
        for (int n = 0; n < 4; ++n) {
          const float p = __expf(sacc[m][n][r] - mnew);
          sacc[m][n][r] = p;
          ps += p;
        }
        ps += __shfl_xor(ps, 1);
        ps += __shfl_xor(ps, 2);
        ps += __shfl_xor(ps, 4);
        ps += __shfl_xor(ps, 8);
        lrun[m][r] = lrun[m][r] * corr + ps;
#pragma unroll
        for (int nd = 0; nd < 4; ++nd) o[m][nd][r] *= corr;
        const int prow = m * 16 + g * 4 + r;
#pragma unroll
        for (int n = 0; n < 4; ++n)
          Plds[w][prow * 72 + n * 16 + c] = f2b(sacc[m][n][r]);
      }

    // ---- O += P @ V
#pragma unroll
    for (int kk = 0; kk < 2; ++kk) {
      b16x8 pf[2];
#pragma unroll
      for (int m = 0; m < 2; ++m)
        pf[m] = *(const b16x8*)&Plds[w][(m * 16 + c) * 72 + kk * 32 + g * 8];
#pragma unroll
      for (int nd = 0; nd < 4; ++nd) {
        const int d = nd * 16 + c;
        const int chunk = ((kk * 4 + g) ^ (d >> 3)) & 7;
        const b16x8 vf = *(const b16x8*)&Vt[d * 72 + chunk * 8];
#pragma unroll
        for (int m = 0; m < 2; ++m)
          o[m][nd] = mfma_bf16(pf[m], vf, o[m][nd]);
      }
    }
    __syncthreads();
  }

  // ---- normalize and store merged-heads bf16
#pragma unroll
  for (int m = 0; m < 2; ++m)
#pragma unroll
    for (int r = 0; r < 4; ++r) {
      const float inv = 1.f / lrun[m][r];
      const int row = qbase + w * 32 + m * 16 + g * 4 + r;
#pragma unroll
      for (int nd = 0; nd < 4; ++nd)
        O[base_bh + (size_t)row * E_DIM + nd * 16 + c] = f2b(o[m][nd][r] * inv);
    }
}

// ------------------------------------------------------------------- launch

extern "C" void kernel_launch(void* const* d_in, const int* in_sizes, int n_in,
                              void* d_out, int out_size, void* d_ws,
                              size_t ws_size, hipStream_t stream) {
  const float* X = (const float*)d_in[0];
  const float* Wq = (const float*)d_in[1];
  const float* bq = (const float*)d_in[2];
  const float* Wk = (const float*)d_in[3];
  const float* bk = (const float*)d_in[4];
  const float* Wv = (const float*)d_in[5];
  const float* bv = (const float*)d_in[6];
  const float* Wo = (const float*)d_in[7];
  const float* bo = (const float*)d_in[8];
  float* out = (float*)d_out;

  unsigned short* ws = (unsigned short*)d_ws;
  unsigned short* Xb = ws;                     // 8388608 (aliased by Ab later)
  unsigned short* Wqt = Xb + 8388608;          // 1048576
  unsigned short* Wkt = Wqt + 1048576;
  unsigned short* Wvt = Wkt + 1048576;
  unsigned short* Wot = Wvt + 1048576;
  unsigned short* Qb = Wot + 1048576;          // 8388608
  unsigned short* Kb = Qb + 8388608;
  unsigned short* Vb = Kb + 8388608;
  unsigned short* Ab = Xb;                     // alias: X dead after V gemm

  f32_to_bf16_kernel<<<8192, 256, 0, stream>>>(X, Xb, 2097152);
  dim3 tg(32, 32);
  transpose_w_kernel<<<tg, 256, 0, stream>>>(Wq, Wqt);
  transpose_w_kernel<<<tg, 256, 0, stream>>>(Wk, Wkt);
  transpose_w_kernel<<<tg, 256, 0, stream>>>(Wv, Wvt);
  transpose_w_kernel<<<tg, 256, 0, stream>>>(Wo, Wot);

  dim3 gg(M_ROWS / 128, E_DIM / 128);  // 64 x 8
  gemm_bt_kernel<0><<<gg, 256, 0, stream>>>(Xb, Wqt, bq, (void*)Qb, M_ROWS, E_DIM, E_DIM);
  gemm_bt_kernel<0><<<gg, 256, 0, stream>>>(Xb, Wkt, bk, (void*)Kb, M_ROWS, E_DIM, E_DIM);
  gemm_bt_kernel<0><<<gg, 256, 0, stream>>>(Xb, Wvt, bv, (void*)Vb, M_ROWS, E_DIM, E_DIM);

  dim3 ga(S_LEN / 128, 4 * H_NUM);  // 16 x 64
  attn_kernel<<<ga, 256, 0, stream>>>(Qb, Kb, Vb, Ab);

  gemm_bt_kernel<1><<<gg, 256, 0, stream>>>(Ab, Wot, bo, (void*)out, M_ROWS, E_DIM, E_DIM);
}

// Round 8
// 408.075 us; speedup vs baseline: 1.2616x; 1.2616x over previous
//
#include <hip/hip_runtime.h>
#include <hip/hip_bf16.h>

// MHA: B=4, S=2048, E=1024, H=16, D=64. f32 in/out, bf16 MFMA internally.
//
// Pipeline (all in d_ws, bf16 storage as ushort):
//   Xb   = bf16(X)                     [8192,1024]
//   W*t  = bf16(W*^T)                  [1024,1024] (N,K layout for B^T GEMM)
//   Q/K/Vb = Xb @ W*t + b*             [8192,1024]  (Q pre-scaled by 0.125)
//   Ab   = flash_attention(Qb,Kb,Vb)   [8192,1024]  (merged-heads layout)
//   out  = Ab @ Wot + bo               [8192,1024]  f32
//
// attn v2: swapped QK^T (mfma(K,Q)) -> S[k-local=g*4+r][q=c]; in-register
// softmax (2-shfl row reduce); P->PV-A-fragment via cvt_pk + bpermute
// exchange (no P LDS round-trip; LDS 36->18 KB); async-STAGE K/V (load
// next tile to regs during compute, write LDS after barrier).

#define S_LEN 2048
#define E_DIM 1024
#define H_NUM 16
#define D_DIM 64
#define M_ROWS 8192  // B*S
#define NT (S_LEN / 64)

typedef float f32x4 __attribute__((ext_vector_type(4)));
typedef __bf16 b16x8 __attribute__((ext_vector_type(8)));
typedef unsigned short u16x8 __attribute__((ext_vector_type(8)));
typedef unsigned short u16x4 __attribute__((ext_vector_type(4)));
typedef unsigned int u32x4 __attribute__((ext_vector_type(4)));

static __device__ __forceinline__ f32x4 mfma_bf16(b16x8 a, b16x8 b, f32x4 c) {
  return __builtin_amdgcn_mfma_f32_16x16x32_bf16(a, b, c, 0, 0, 0);
}

// f32 -> bf16 round-to-nearest-even
static __device__ __forceinline__ unsigned short f2b(float f) {
  union { float f; unsigned u; } v;
  v.f = f;
  unsigned r = v.u + 0x7fffu + ((v.u >> 16) & 1u);
  return (unsigned short)(r >> 16);
}

// pack two f32 -> one u32 of 2 bf16 (lo = a, hi = b)
static __device__ __forceinline__ unsigned pack_bf16x2(float a, float b) {
  __hip_bfloat162 h2 = __float22bfloat162_rn(make_float2(a, b));
  union { __hip_bfloat162 h; unsigned u; } p;
  p.h = h2;
  return p.u;
}

// async global->LDS, 16B per lane; lds dest must be wave-uniform base.
static __device__ __forceinline__ void async_ld16(const unsigned short* g,
                                                  const unsigned short* lds) {
  __builtin_amdgcn_global_load_lds(
      (const __attribute__((address_space(1))) void*)g,
      (__attribute__((address_space(3))) void*)lds, 16, 0, 0);
}

// ---------------------------------------------------------------- conversions

__global__ __launch_bounds__(256) void f32_to_bf16_kernel(
    const float* __restrict__ in, unsigned short* __restrict__ out, int n4) {
  const int i = blockIdx.x * 256 + threadIdx.x;
  if (i >= n4) return;
  const f32x4 v = *(const f32x4*)&in[(size_t)i * 4];
  u16x4 o;
  o.x = f2b(v.x); o.y = f2b(v.y); o.z = f2b(v.z); o.w = f2b(v.w);
  *(u16x4*)&out[(size_t)i * 4] = o;
}

// W [1024,1024] f32 row-major -> Wt [1024,1024] bf16 (Wt[n][k] = W[k][n])
__global__ __launch_bounds__(256) void transpose_w_kernel(
    const float* __restrict__ in, unsigned short* __restrict__ out) {
  __shared__ float tile[32][33];
  const int bx = blockIdx.x * 32, by = blockIdx.y * 32;
  const int tx = threadIdx.x & 31;
  const int ty = (threadIdx.x >> 5) * 4;  // 8 groups x 4 rows
#pragma unroll
  for (int i = 0; i < 4; ++i)
    tile[ty + i][tx] = in[(size_t)(by + ty + i) * 1024 + bx + tx];
  __syncthreads();
#pragma unroll
  for (int i = 0; i < 4; ++i)
    out[(size_t)(bx + ty + i) * 1024 + by + tx] = f2b(tile[tx][ty + i]);
}

// ------------------------------------------------------------------ GEMM B^T
// C[M,N] = (A[M,K] @ Bt[N,K]^T + bias) * scale.  128x128 tile, BK=32,
// 4 waves (2x2), each wave 64x64 = 4x4 fragments of 16x16x32.

template <int OUT_F32>
__global__ __launch_bounds__(256) void gemm_bt_kernel(
    const unsigned short* __restrict__ A, const unsigned short* __restrict__ Bt,
    const float* __restrict__ bias, void* __restrict__ Cout, int M, int N,
    int K, float scale) {
  __shared__ __align__(16) unsigned short As[128 * 32];
  __shared__ __align__(16) unsigned short Bs[128 * 32];

  const int tid = threadIdx.x;
  const int wid = tid >> 6;
  const int l = tid & 63;
  const int g = l >> 4;
  const int c = l & 15;
  const int wm = wid >> 1;
  const int wn = wid & 1;
  const int mbase = blockIdx.x * 128;
  const int nbase = blockIdx.y * 128;
  const int lrow = l >> 2;        // 0..15 within 16-row chunk
  const int scol = (l & 3) * 8;   // 0,8,16,24

  f32x4 acc[4][4];
#pragma unroll
  for (int i = 0; i < 4; ++i)
#pragma unroll
    for (int j = 0; j < 4; ++j) acc[i][j] = (f32x4){0.f, 0.f, 0.f, 0.f};

  for (int kt = 0; kt < K; kt += 32) {
#pragma unroll
    for (int i = 0; i < 2; ++i) {
      const int ci = wid * 2 + i;        // 0..7, wave-uniform
      const int row = ci * 16 + lrow;    // 0..127
      async_ld16(A + (size_t)(mbase + row) * K + kt + scol, As + ci * 512);
      async_ld16(Bt + (size_t)(nbase + row) * K + kt + scol, Bs + ci * 512);
    }
    __syncthreads();

    b16x8 af[4], bfr[4];
#pragma unroll
    for (int mi = 0; mi < 4; ++mi)
      af[mi] = *(const b16x8*)&As[(wm * 64 + mi * 16 + c) * 32 + g * 8];
#pragma unroll
    for (int ni = 0; ni < 4; ++ni)
      bfr[ni] = *(const b16x8*)&Bs[(wn * 64 + ni * 16 + c) * 32 + g * 8];
#pragma unroll
    for (int mi = 0; mi < 4; ++mi)
#pragma unroll
      for (int ni = 0; ni < 4; ++ni)
        acc[mi][ni] = mfma_bf16(af[mi], bfr[ni], acc[mi][ni]);
    __syncthreads();
  }

#pragma unroll
  for (int ni = 0; ni < 4; ++ni) {
    const int col = nbase + wn * 64 + ni * 16 + c;
    const float bv = bias[col];
#pragma unroll
    for (int mi = 0; mi < 4; ++mi)
#pragma unroll
      for (int r = 0; r < 4; ++r) {
        const int row = mbase + wm * 64 + mi * 16 + g * 4 + r;
        const float v = (acc[mi][ni][r] + bv) * scale;
        if (OUT_F32)
          ((float*)Cout)[(size_t)row * N + col] = v;
        else
          ((unsigned short*)Cout)[(size_t)row * N + col] = f2b(v);
      }
  }
}

// ----------------------------------------------------------- flash attention
// Grid (S/128, B*H). 4 waves x 32 q-rows. KV tile = 64 rows.
// Swapped QK^T: sacc[n][m] = mfma(kf, qf) -> S[k=n*16+g*4+r][q=m*16+c].
// Softmax stats per lane for q-row m*16+c (g-replicated via 2 shfl_xor).
// P -> PV A-fragment: pack pairs (cvt_pk), bpermute from g-groups
// {(2g)&3, (2g+1)&3}, flavor n = 2*kk + (g>>1) selected per lane.
// V in LDS transposed + chunk-XOR swizzle (unchanged, verified).
// Async-STAGE: next tile's K/V loaded to regs during compute.

__global__ __launch_bounds__(256) void attn_kernel(
    const unsigned short* __restrict__ Q, const unsigned short* __restrict__ K,
    const unsigned short* __restrict__ V, unsigned short* __restrict__ O) {
  __shared__ __align__(16) unsigned short Klds[64 * 72];
  __shared__ __align__(16) unsigned short Vt[64 * 72];  // [d][kv] swizzled

  const int tid = threadIdx.x;
  const int w = tid >> 6;
  const int l = tid & 63;
  const int g = l >> 4;
  const int c = l & 15;
  const int b = blockIdx.y >> 4;
  const int h = blockIdx.y & 15;
  const int qbase = blockIdx.x * 128;
  const size_t base_bh = (size_t)b * S_LEN * E_DIM + h * D_DIM;

  // staging thread geometry
  const int srow0 = tid >> 3;            // kv row for i=0
  const int scolc = (tid & 7) * 8;       // d chunk base
  const int schunk = scolc >> 3;

  // Q fragments (Q pre-scaled by 0.125 in projection GEMM)
  b16x8 qf[2][2];
#pragma unroll
  for (int m = 0; m < 2; ++m)
#pragma unroll
    for (int kk = 0; kk < 2; ++kk) {
      const int row = qbase + w * 32 + m * 16 + c;
      qf[m][kk] = *(const b16x8*)&Q[base_bh + (size_t)row * E_DIM + kk * 32 + g * 8];
    }

  f32x4 o[2][4];
#pragma unroll
  for (int m = 0; m < 2; ++m)
#pragma unroll
    for (int nd = 0; nd < 4; ++nd) o[m][nd] = (f32x4){0.f, 0.f, 0.f, 0.f};
  float mrun[2], lrun[2];
  mrun[0] = mrun[1] = -3.0e38f;
  lrun[0] = lrun[1] = 0.f;

  u16x8 kreg[2], vreg[2];

  // ---- staging helpers
#define LOAD_TILE(T)                                                        \
  {                                                                         \
    const int kvb_ = (T) * 64;                                              \
    _Pragma("unroll") for (int i = 0; i < 2; ++i) {                         \
      const int row_ = srow0 + i * 32;                                      \
      const size_t ga_ = base_bh + (size_t)(kvb_ + row_) * E_DIM + scolc;   \
      kreg[i] = *(const u16x8*)&K[ga_];                                     \
      vreg[i] = *(const u16x8*)&V[ga_];                                     \
    }                                                                       \
  }
#define WRITE_TILE()                                                        \
  {                                                                         \
    _Pragma("unroll") for (int i = 0; i < 2; ++i) {                         \
      const int row_ = srow0 + i * 32;                                      \
      *(u16x8*)&Klds[row_ * 72 + scolc] = kreg[i];                          \
      const int chunk_ = ((row_ >> 3) ^ schunk) & 7;                        \
      _Pragma("unroll") for (int j = 0; j < 8; ++j)                         \
          Vt[(scolc + j) * 72 + chunk_ * 8 + (row_ & 7)] = vreg[i][j];      \
    }                                                                       \
  }

  LOAD_TILE(0);
  WRITE_TILE();

  const int srcA = (((2 * g) & 3) << 4) + c;
  const int srcB = (((2 * g + 1) & 3) << 4) + c;
  const int fsel = g >> 1;

  for (int t = 0; t < NT; ++t) {
    if (t + 1 < NT) LOAD_TILE(t + 1);
    __syncthreads();  // LDS tile t visible

    // ---- S^T = K Q^T  (S[k-local][q-local])
    f32x4 sacc[4][2];
#pragma unroll
    for (int n = 0; n < 4; ++n)
#pragma unroll
      for (int m = 0; m < 2; ++m) sacc[n][m] = (f32x4){0.f, 0.f, 0.f, 0.f};
#pragma unroll
    for (int n = 0; n < 4; ++n)
#pragma unroll
      for (int kk = 0; kk < 2; ++kk) {
        const b16x8 kf = *(const b16x8*)&Klds[(n * 16 + c) * 72 + kk * 32 + g * 8];
#pragma unroll
        for (int m = 0; m < 2; ++m)
          sacc[n][m] = mfma_bf16(kf, qf[m][kk], sacc[n][m]);
      }

    // ---- softmax + PV per m-block
#pragma unroll
    for (int m = 0; m < 2; ++m) {
      float mx = sacc[0][m][0];
#pragma unroll
      for (int n = 0; n < 4; ++n)
#pragma unroll
        for (int r = 0; r < 4; ++r) mx = fmaxf(mx, sacc[n][m][r]);
      mx = fmaxf(mx, __shfl_xor(mx, 16));
      mx = fmaxf(mx, __shfl_xor(mx, 32));
      const float mnew = fmaxf(mrun[m], mx);
      const float corr = __expf(mrun[m] - mnew);
      mrun[m] = mnew;
      float ps = 0.f;
#pragma unroll
      for (int n = 0; n < 4; ++n)
#pragma unroll
        for (int r = 0; r < 4; ++r) {
          const float p = __expf(sacc[n][m][r] - mnew);
          sacc[n][m][r] = p;
          ps += p;
        }
      ps += __shfl_xor(ps, 16);
      ps += __shfl_xor(ps, 32);
      lrun[m] = lrun[m] * corr + ps;

      // O rescale: o rows are q = g*4+r; stats live at lane c=q.
#pragma unroll
      for (int r = 0; r < 4; ++r) {
        const float cr = __shfl(corr, g * 20 + r);  // lane g*16 + (g*4+r)
#pragma unroll
        for (int nd = 0; nd < 4; ++nd) o[m][nd][r] *= cr;
      }

      // pack P pairs: wpk[n][rr] = bf16x2(P[k=n*16+g*4+2rr], ..+2rr+1)
      unsigned wpk[4][2];
#pragma unroll
      for (int n = 0; n < 4; ++n)
#pragma unroll
        for (int rr = 0; rr < 2; ++rr)
          wpk[n][rr] = pack_bf16x2(sacc[n][m][2 * rr], sacc[n][m][2 * rr + 1]);

#pragma unroll
      for (int kk = 0; kk < 2; ++kk) {
        // exchange: need from srcA/srcB their wpk[n][0..1], n = 2kk+(g>>1)
        const unsigned aL0 = (unsigned)__shfl((int)wpk[2 * kk][0], srcA);
        const unsigned aL1 = (unsigned)__shfl((int)wpk[2 * kk][1], srcA);
        const unsigned bL0 = (unsigned)__shfl((int)wpk[2 * kk + 1][0], srcA);
        const unsigned bL1 = (unsigned)__shfl((int)wpk[2 * kk + 1][1], srcA);
        const unsigned aH0 = (unsigned)__shfl((int)wpk[2 * kk][0], srcB);
        const unsigned aH1 = (unsigned)__shfl((int)wpk[2 * kk][1], srcB);
        const unsigned bH0 = (unsigned)__shfl((int)wpk[2 * kk + 1][0], srcB);
        const unsigned bH1 = (unsigned)__shfl((int)wpk[2 * kk + 1][1], srcB);
        union { u32x4 u; b16x8 bv; } pun;
        pun.u = (u32x4){fsel ? bL0 : aL0, fsel ? bL1 : aL1,
                        fsel ? bH0 : aH0, fsel ? bH1 : aH1};
        const b16x8 pf = pun.bv;
#pragma unroll
        for (int nd = 0; nd < 4; ++nd) {
          const int d = nd * 16 + c;
          const int chunk = ((kk * 4 + g) ^ (d >> 3)) & 7;
          const b16x8 vf = *(const b16x8*)&Vt[d * 72 + chunk * 8];
          o[m][nd] = mfma_bf16(pf, vf, o[m][nd]);
        }
      }
    }

    __syncthreads();  // all reads of tile t done
    if (t + 1 < NT) WRITE_TILE();
  }

  // ---- normalize and store merged-heads bf16
#pragma unroll
  for (int m = 0; m < 2; ++m) {
    const float inv = 1.f / lrun[m];
#pragma unroll
    for (int r = 0; r < 4; ++r) {
      const float ivr = __shfl(inv, g * 20 + r);
      const int row = qbase + w * 32 + m * 16 + g * 4 + r;
#pragma unroll
      for (int nd = 0; nd < 4; ++nd)
        O[base_bh + (size_t)row * E_DIM + nd * 16 + c] = f2b(o[m][nd][r] * ivr);
    }
  }
#undef LOAD_TILE
#undef WRITE_TILE
}

// ------------------------------------------------------------------- launch

extern "C" void kernel_launch(void* const* d_in, const int* in_sizes, int n_in,
                              void* d_out, int out_size, void* d_ws,
                              size_t ws_size, hipStream_t stream) {
  const float* X = (const float*)d_in[0];
  const float* Wq = (const float*)d_in[1];
  const float* bq = (const float*)d_in[2];
  const float* Wk = (const float*)d_in[3];
  const float* bk = (const float*)d_in[4];
  const float* Wv = (const float*)d_in[5];
  const float* bv = (const float*)d_in[6];
  const float* Wo = (const float*)d_in[7];
  const float* bo = (const float*)d_in[8];
  float* out = (float*)d_out;

  unsigned short* ws = (unsigned short*)d_ws;
  unsigned short* Xb = ws;                     // 8388608 (aliased by Ab later)
  unsigned short* Wqt = Xb + 8388608;          // 1048576
  unsigned short* Wkt = Wqt + 1048576;
  unsigned short* Wvt = Wkt + 1048576;
  unsigned short* Wot = Wvt + 1048576;
  unsigned short* Qb = Wot + 1048576;          // 8388608
  unsigned short* Kb = Qb + 8388608;
  unsigned short* Vb = Kb + 8388608;
  unsigned short* Ab = Xb;                     // alias: X dead after V gemm

  f32_to_bf16_kernel<<<8192, 256, 0, stream>>>(X, Xb, 2097152);
  dim3 tg(32, 32);
  transpose_w_kernel<<<tg, 256, 0, stream>>>(Wq, Wqt);
  transpose_w_kernel<<<tg, 256, 0, stream>>>(Wk, Wkt);
  transpose_w_kernel<<<tg, 256, 0, stream>>>(Wv, Wvt);
  transpose_w_kernel<<<tg, 256, 0, stream>>>(Wo, Wot);

  dim3 gg(M_ROWS / 128, E_DIM / 128);  // 64 x 8
  gemm_bt_kernel<0><<<gg, 256, 0, stream>>>(Xb, Wqt, bq, (void*)Qb, M_ROWS,
                                            E_DIM, E_DIM, 0.125f);
  gemm_bt_kernel<0><<<gg, 256, 0, stream>>>(Xb, Wkt, bk, (void*)Kb, M_ROWS,
                                            E_DIM, E_DIM, 1.0f);
  gemm_bt_kernel<0><<<gg, 256, 0, stream>>>(Xb, Wvt, bv, (void*)Vb, M_ROWS,
                                            E_DIM, E_DIM, 1.0f);

  dim3 ga(S_LEN / 128, 4 * H_NUM);  // 16 x 64
  attn_kernel<<<ga, 256, 0, stream>>>(Qb, Kb, Vb, Ab);

  gemm_bt_kernel<1><<<gg, 256, 0, stream>>>(Ab, Wot, bo, (void*)out, M_ROWS,
                                            E_DIM, E_DIM, 1.0f);
}

// Round 9
// 372.766 us; speedup vs baseline: 1.3811x; 1.0947x over previous
//
#include <hip/hip_runtime.h>
#include <hip/hip_bf16.h>

// MHA: B=4, S=2048, E=1024, H=16, D=64. f32 in/out, bf16 MFMA internally.
//
// Pipeline:
//   Xb    = bf16(X)                      [8192,1024]
//   W*t   = bf16(W*^T)                   [1024,1024] x4 (QKV contiguous)
//   QKVb  = Xb @ [Wq|Wk|Wv]^T + b        [8192,3072]  (Q cols pre-scaled 1/8)
//   Ab    = flash_attention(QKVb)        [8192,1024]  (aliases Xb)
//   out   = Ab @ Wot + bo                [8192,1024]  f32
//
// attn v3: swapped QK^T in-reg softmax (verified v2 math), double-buffered
// K/V LDS (1 barrier/tile), PV kk-outer (Vt reads halved), setprio on MFMA.

#define S_LEN 2048
#define E_DIM 1024
#define H_NUM 16
#define D_DIM 64
#define M_ROWS 8192
#define NT (S_LEN / 64)
#define QKV_LD 3072

typedef float f32x4 __attribute__((ext_vector_type(4)));
typedef __bf16 b16x8 __attribute__((ext_vector_type(8)));
typedef unsigned short u16x8 __attribute__((ext_vector_type(8)));
typedef unsigned short u16x4 __attribute__((ext_vector_type(4)));
typedef unsigned int u32x4 __attribute__((ext_vector_type(4)));

static __device__ __forceinline__ f32x4 mfma_bf16(b16x8 a, b16x8 b, f32x4 c) {
  return __builtin_amdgcn_mfma_f32_16x16x32_bf16(a, b, c, 0, 0, 0);
}

static __device__ __forceinline__ unsigned short f2b(float f) {
  union { float f; unsigned u; } v;
  v.f = f;
  unsigned r = v.u + 0x7fffu + ((v.u >> 16) & 1u);
  return (unsigned short)(r >> 16);
}

static __device__ __forceinline__ unsigned pack_bf16x2(float a, float b) {
  __hip_bfloat162 h2 = __float22bfloat162_rn(make_float2(a, b));
  union { __hip_bfloat162 h; unsigned u; } p;
  p.h = h2;
  return p.u;
}

static __device__ __forceinline__ void async_ld16(const unsigned short* g,
                                                  const unsigned short* lds) {
  __builtin_amdgcn_global_load_lds(
      (const __attribute__((address_space(1))) void*)g,
      (__attribute__((address_space(3))) void*)lds, 16, 0, 0);
}

// ---------------------------------------------------------------- conversions

__global__ __launch_bounds__(256) void f32_to_bf16_kernel(
    const float* __restrict__ in, unsigned short* __restrict__ out, int n4) {
  const int i = blockIdx.x * 256 + threadIdx.x;
  if (i >= n4) return;
  const f32x4 v = *(const f32x4*)&in[(size_t)i * 4];
  u16x4 o;
  o.x = f2b(v.x); o.y = f2b(v.y); o.z = f2b(v.z); o.w = f2b(v.w);
  *(u16x4*)&out[(size_t)i * 4] = o;
}

__global__ __launch_bounds__(256) void transpose_w_kernel(
    const float* __restrict__ in, unsigned short* __restrict__ out) {
  __shared__ float tile[32][33];
  const int bx = blockIdx.x * 32, by = blockIdx.y * 32;
  const int tx = threadIdx.x & 31;
  const int ty = (threadIdx.x >> 5) * 4;
#pragma unroll
  for (int i = 0; i < 4; ++i)
    tile[ty + i][tx] = in[(size_t)(by + ty + i) * 1024 + bx + tx];
  __syncthreads();
#pragma unroll
  for (int i = 0; i < 4; ++i)
    out[(size_t)(bx + ty + i) * 1024 + by + tx] = f2b(tile[tx][ty + i]);
}

// ------------------------------------------------------------------ GEMM B^T
// Generic: C[M,N] = (A @ Bt^T + bias) * scale (f32 out, for Wo projection).

__global__ __launch_bounds__(256) void gemm_bt_f32_kernel(
    const unsigned short* __restrict__ A, const unsigned short* __restrict__ Bt,
    const float* __restrict__ bias, float* __restrict__ Cout, int M, int N,
    int K) {
  __shared__ __align__(16) unsigned short As[128 * 32];
  __shared__ __align__(16) unsigned short Bs[128 * 32];

  const int tid = threadIdx.x;
  const int wid = tid >> 6;
  const int l = tid & 63;
  const int g = l >> 4;
  const int c = l & 15;
  const int wm = wid >> 1;
  const int wn = wid & 1;
  const int mbase = blockIdx.x * 128;
  const int nbase = blockIdx.y * 128;
  const int lrow = l >> 2;
  const int scol = (l & 3) * 8;

  f32x4 acc[4][4];
#pragma unroll
  for (int i = 0; i < 4; ++i)
#pragma unroll
    for (int j = 0; j < 4; ++j) acc[i][j] = (f32x4){0.f, 0.f, 0.f, 0.f};

  for (int kt = 0; kt < K; kt += 32) {
#pragma unroll
    for (int i = 0; i < 2; ++i) {
      const int ci = wid * 2 + i;
      const int row = ci * 16 + lrow;
      async_ld16(A + (size_t)(mbase + row) * K + kt + scol, As + ci * 512);
      async_ld16(Bt + (size_t)(nbase + row) * K + kt + scol, Bs + ci * 512);
    }
    __syncthreads();

    b16x8 af[4], bfr[4];
#pragma unroll
    for (int mi = 0; mi < 4; ++mi)
      af[mi] = *(const b16x8*)&As[(wm * 64 + mi * 16 + c) * 32 + g * 8];
#pragma unroll
    for (int ni = 0; ni < 4; ++ni)
      bfr[ni] = *(const b16x8*)&Bs[(wn * 64 + ni * 16 + c) * 32 + g * 8];
#pragma unroll
    for (int mi = 0; mi < 4; ++mi)
#pragma unroll
      for (int ni = 0; ni < 4; ++ni)
        acc[mi][ni] = mfma_bf16(af[mi], bfr[ni], acc[mi][ni]);
    __syncthreads();
  }

#pragma unroll
  for (int ni = 0; ni < 4; ++ni) {
    const int col = nbase + wn * 64 + ni * 16 + c;
    const float bv = bias[col];
#pragma unroll
    for (int mi = 0; mi < 4; ++mi)
#pragma unroll
      for (int r = 0; r < 4; ++r) {
        const int row = mbase + wm * 64 + mi * 16 + g * 4 + r;
        Cout[(size_t)row * N + col] = acc[mi][ni][r] + bv;
      }
  }
}

// Fused QKV: M=8192, N=3072, K=1024; bias/scale per 1024-col segment;
// bf16 out to [8192][3072].
__global__ __launch_bounds__(256) void gemm_qkv_kernel(
    const unsigned short* __restrict__ A, const unsigned short* __restrict__ Bt,
    const float* __restrict__ bq, const float* __restrict__ bk,
    const float* __restrict__ bv, unsigned short* __restrict__ Cout) {
  const int M = M_ROWS, N = QKV_LD, K = E_DIM;
  __shared__ __align__(16) unsigned short As[128 * 32];
  __shared__ __align__(16) unsigned short Bs[128 * 32];

  const int tid = threadIdx.x;
  const int wid = tid >> 6;
  const int l = tid & 63;
  const int g = l >> 4;
  const int c = l & 15;
  const int wm = wid >> 1;
  const int wn = wid & 1;
  const int mbase = blockIdx.x * 128;
  const int nbase = blockIdx.y * 128;
  const int lrow = l >> 2;
  const int scol = (l & 3) * 8;

  f32x4 acc[4][4];
#pragma unroll
  for (int i = 0; i < 4; ++i)
#pragma unroll
    for (int j = 0; j < 4; ++j) acc[i][j] = (f32x4){0.f, 0.f, 0.f, 0.f};

  for (int kt = 0; kt < K; kt += 32) {
#pragma unroll
    for (int i = 0; i < 2; ++i) {
      const int ci = wid * 2 + i;
      const int row = ci * 16 + lrow;
      async_ld16(A + (size_t)(mbase + row) * K + kt + scol, As + ci * 512);
      async_ld16(Bt + (size_t)(nbase + row) * K + kt + scol, Bs + ci * 512);
    }
    __syncthreads();

    b16x8 af[4], bfr[4];
#pragma unroll
    for (int mi = 0; mi < 4; ++mi)
      af[mi] = *(const b16x8*)&As[(wm * 64 + mi * 16 + c) * 32 + g * 8];
#pragma unroll
    for (int ni = 0; ni < 4; ++ni)
      bfr[ni] = *(const b16x8*)&Bs[(wn * 64 + ni * 16 + c) * 32 + g * 8];
#pragma unroll
    for (int mi = 0; mi < 4; ++mi)
#pragma unroll
      for (int ni = 0; ni < 4; ++ni)
        acc[mi][ni] = mfma_bf16(af[mi], bfr[ni], acc[mi][ni]);
    __syncthreads();
  }

#pragma unroll
  for (int ni = 0; ni < 4; ++ni) {
    const int col = nbase + wn * 64 + ni * 16 + c;
    const float* bp = (col < 1024) ? bq : ((col < 2048) ? bk : bv);
    const float bvv = bp[col & 1023];
    const float scale = (col < 1024) ? 0.125f : 1.0f;
#pragma unroll
    for (int mi = 0; mi < 4; ++mi)
#pragma unroll
      for (int r = 0; r < 4; ++r) {
        const int row = mbase + wm * 64 + mi * 16 + g * 4 + r;
        Cout[(size_t)row * N + col] = f2b((acc[mi][ni][r] + bvv) * scale);
      }
  }
}

// ----------------------------------------------------------- flash attention
// Grid (S/128, B*H). 4 waves x 32 q-rows. KV tile = 64 rows. Double-buffered.
// Swapped QK^T: sacc[n][m] = mfma(kf, qf) -> S[k=n*16+g*4+r][q=m*16+c].
// P -> PV A-fragment via pack + shfl exchange (v2-verified network).

__global__ __launch_bounds__(256) void attn_kernel(
    const unsigned short* __restrict__ QKV, unsigned short* __restrict__ O) {
  __shared__ __align__(16) unsigned short Klds[2][64 * 72];
  __shared__ __align__(16) unsigned short Vt[2][64 * 72];  // [d][kv] swizzled

  const int tid = threadIdx.x;
  const int w = tid >> 6;
  const int l = tid & 63;
  const int g = l >> 4;
  const int c = l & 15;
  const int b = blockIdx.y >> 4;
  const int h = blockIdx.y & 15;
  const int qbase = blockIdx.x * 128;
  const size_t base_bh = (size_t)b * S_LEN * QKV_LD + h * D_DIM;
  const unsigned short* Q = QKV;
  const unsigned short* K = QKV + 1024;
  const unsigned short* V = QKV + 2048;

  const int srow0 = tid >> 3;
  const int scolc = (tid & 7) * 8;
  const int schunk = scolc >> 3;

  // Q fragments (Q pre-scaled by 0.125 in projection GEMM)
  b16x8 qf[2][2];
#pragma unroll
  for (int m = 0; m < 2; ++m)
#pragma unroll
    for (int kk = 0; kk < 2; ++kk) {
      const int row = qbase + w * 32 + m * 16 + c;
      qf[m][kk] =
          *(const b16x8*)&Q[base_bh + (size_t)row * QKV_LD + kk * 32 + g * 8];
    }

  f32x4 o[2][4];
#pragma unroll
  for (int m = 0; m < 2; ++m)
#pragma unroll
    for (int nd = 0; nd < 4; ++nd) o[m][nd] = (f32x4){0.f, 0.f, 0.f, 0.f};
  float mrun[2], lrun[2];
  mrun[0] = mrun[1] = -3.0e38f;
  lrun[0] = lrun[1] = 0.f;

  u16x8 kreg[2], vreg[2];

#define LOAD_TILE(T)                                                         \
  {                                                                          \
    const int kvb_ = (T) * 64;                                               \
    _Pragma("unroll") for (int i = 0; i < 2; ++i) {                          \
      const int row_ = srow0 + i * 32;                                       \
      const size_t ga_ = base_bh + (size_t)(kvb_ + row_) * QKV_LD + scolc;   \
      kreg[i] = *(const u16x8*)&K[ga_];                                      \
      vreg[i] = *(const u16x8*)&V[ga_];                                      \
    }                                                                        \
  }
#define WRITE_TILE(BUF)                                                      \
  {                                                                          \
    _Pragma("unroll") for (int i = 0; i < 2; ++i) {                          \
      const int row_ = srow0 + i * 32;                                       \
      *(u16x8*)&Klds[BUF][row_ * 72 + scolc] = kreg[i];                      \
      const int chunk_ = ((row_ >> 3) ^ schunk) & 7;                         \
      _Pragma("unroll") for (int j = 0; j < 8; ++j)                          \
          Vt[BUF][(scolc + j) * 72 + chunk_ * 8 + (row_ & 7)] = vreg[i][j];  \
    }                                                                        \
  }

  LOAD_TILE(0);
  WRITE_TILE(0);

  const int srcA = (((2 * g) & 3) << 4) + c;
  const int srcB = (((2 * g + 1) & 3) << 4) + c;
  const int fsel = g >> 1;

  for (int t = 0; t < NT; ++t) {
    const int cur = t & 1;
    __syncthreads();  // buf[cur] written (t-1); buf[cur^1] reads done (t-1)

    if (t + 1 < NT) LOAD_TILE(t + 1);

    // ---- S^T = K Q^T
    f32x4 sacc[4][2];
#pragma unroll
    for (int n = 0; n < 4; ++n)
#pragma unroll
      for (int m = 0; m < 2; ++m) sacc[n][m] = (f32x4){0.f, 0.f, 0.f, 0.f};
    __builtin_amdgcn_s_setprio(1);
#pragma unroll
    for (int n = 0; n < 4; ++n)
#pragma unroll
      for (int kk = 0; kk < 2; ++kk) {
        const b16x8 kf =
            *(const b16x8*)&Klds[cur][(n * 16 + c) * 72 + kk * 32 + g * 8];
#pragma unroll
        for (int m = 0; m < 2; ++m)
          sacc[n][m] = mfma_bf16(kf, qf[m][kk], sacc[n][m]);
      }
    __builtin_amdgcn_s_setprio(0);

    // stage t+1 into the idle buffer (vmcnt wait hidden under QK^T)
    if (t + 1 < NT) WRITE_TILE(cur ^ 1);

    // ---- softmax (stats at lane c = q-row; g-replicated)
#pragma unroll
    for (int m = 0; m < 2; ++m) {
      float mx = sacc[0][m][0];
#pragma unroll
      for (int n = 0; n < 4; ++n)
#pragma unroll
        for (int r = 0; r < 4; ++r) mx = fmaxf(mx, sacc[n][m][r]);
      mx = fmaxf(mx, __shfl_xor(mx, 16));
      mx = fmaxf(mx, __shfl_xor(mx, 32));
      const float mnew = fmaxf(mrun[m], mx);
      const float corr = __expf(mrun[m] - mnew);
      mrun[m] = mnew;
      float ps = 0.f;
#pragma unroll
      for (int n = 0; n < 4; ++n)
#pragma unroll
        for (int r = 0; r < 4; ++r) {
          const float p = __expf(sacc[n][m][r] - mnew);
          sacc[n][m][r] = p;
          ps += p;
        }
      ps += __shfl_xor(ps, 16);
      ps += __shfl_xor(ps, 32);
      lrun[m] = lrun[m] * corr + ps;
#pragma unroll
      for (int r = 0; r < 4; ++r) {
        const float cr = __shfl(corr, g * 20 + r);  // lane g*16 + (g*4+r)
#pragma unroll
        for (int nd = 0; nd < 4; ++nd) o[m][nd][r] *= cr;
      }
    }

    // ---- PV: kk outer, vf read once, feeds both m
#pragma unroll
    for (int kk = 0; kk < 2; ++kk) {
      b16x8 pf[2];
#pragma unroll
      for (int m = 0; m < 2; ++m) {
        const unsigned w00 = pack_bf16x2(sacc[2 * kk][m][0], sacc[2 * kk][m][1]);
        const unsigned w01 = pack_bf16x2(sacc[2 * kk][m][2], sacc[2 * kk][m][3]);
        const unsigned w10 =
            pack_bf16x2(sacc[2 * kk + 1][m][0], sacc[2 * kk + 1][m][1]);
        const unsigned w11 =
            pack_bf16x2(sacc[2 * kk + 1][m][2], sacc[2 * kk + 1][m][3]);
        const unsigned aL0 = (unsigned)__shfl((int)w00, srcA);
        const unsigned aL1 = (unsigned)__shfl((int)w01, srcA);
        const unsigned bL0 = (unsigned)__shfl((int)w10, srcA);
        const unsigned bL1 = (unsigned)__shfl((int)w11, srcA);
        const unsigned aH0 = (unsigned)__shfl((int)w00, srcB);
        const unsigned aH1 = (unsigned)__shfl((int)w01, srcB);
        const unsigned bH0 = (unsigned)__shfl((int)w10, srcB);
        const unsigned bH1 = (unsigned)__shfl((int)w11, srcB);
        union { u32x4 u; b16x8 bv; } pun;
        pun.u = (u32x4){fsel ? bL0 : aL0, fsel ? bL1 : aL1,
                        fsel ? bH0 : aH0, fsel ? bH1 : aH1};
        pf[m] = pun.bv;
      }
      __builtin_amdgcn_s_setprio(1);
#pragma unroll
      for (int nd = 0; nd < 4; ++nd) {
        const int d = nd * 16 + c;
        const int chunk = ((kk * 4 + g) ^ (d >> 3)) & 7;
        const b16x8 vf = *(const b16x8*)&Vt[cur][d * 72 + chunk * 8];
        o[0][nd] = mfma_bf16(pf[0], vf, o[0][nd]);
        o[1][nd] = mfma_bf16(pf[1], vf, o[1][nd]);
      }
      __builtin_amdgcn_s_setprio(0);
    }
  }

  // ---- normalize and store merged-heads bf16 ([8192][1024] layout)
#pragma unroll
  for (int m = 0; m < 2; ++m) {
    const float inv = 1.f / lrun[m];
#pragma unroll
    for (int r = 0; r < 4; ++r) {
      const float ivr = __shfl(inv, g * 20 + r);
      const int row = qbase + w * 32 + m * 16 + g * 4 + r;
      const size_t obase = (size_t)b * S_LEN * E_DIM + h * D_DIM;
#pragma unroll
      for (int nd = 0; nd < 4; ++nd)
        O[obase + (size_t)row * E_DIM + nd * 16 + c] = f2b(o[m][nd][r] * ivr);
    }
  }
#undef LOAD_TILE
#undef WRITE_TILE
}

// ------------------------------------------------------------------- launch

extern "C" void kernel_launch(void* const* d_in, const int* in_sizes, int n_in,
                              void* d_out, int out_size, void* d_ws,
                              size_t ws_size, hipStream_t stream) {
  const float* X = (const float*)d_in[0];
  const float* Wq = (const float*)d_in[1];
  const float* bq = (const float*)d_in[2];
  const float* Wk = (const float*)d_in[3];
  const float* bk = (const float*)d_in[4];
  const float* Wv = (const float*)d_in[5];
  const float* bv = (const float*)d_in[6];
  const float* Wo = (const float*)d_in[7];
  const float* bo = (const float*)d_in[8];
  float* out = (float*)d_out;

  unsigned short* ws = (unsigned short*)d_ws;
  unsigned short* Xb = ws;                     // 8388608 (aliased by Ab)
  unsigned short* Wqt = Xb + 8388608;          // 3 x 1048576 contiguous
  unsigned short* Wkt = Wqt + 1048576;
  unsigned short* Wvt = Wkt + 1048576;
  unsigned short* Wot = Wvt + 1048576;
  unsigned short* QKVb = Wot + 1048576;        // 25165824 ([8192][3072])
  unsigned short* Ab = Xb;                     // alias: X dead after QKV gemm

  f32_to_bf16_kernel<<<8192, 256, 0, stream>>>(X, Xb, 2097152);
  dim3 tg(32, 32);
  transpose_w_kernel<<<tg, 256, 0, stream>>>(Wq, Wqt);
  transpose_w_kernel<<<tg, 256, 0, stream>>>(Wk, Wkt);
  transpose_w_kernel<<<tg, 256, 0, stream>>>(Wv, Wvt);
  transpose_w_kernel<<<tg, 256, 0, stream>>>(Wo, Wot);

  dim3 gq(M_ROWS / 128, QKV_LD / 128);  // 64 x 24
  gemm_qkv_kernel<<<gq, 256, 0, stream>>>(Xb, Wqt, bq, bk, bv, QKVb);

  dim3 ga(S_LEN / 128, 4 * H_NUM);  // 16 x 64
  attn_kernel<<<ga, 256, 0, stream>>>(QKVb, Ab);

  dim3 gg(M_ROWS / 128, E_DIM / 128);  // 64 x 8
  gemm_bt_f32_kernel<<<gg, 256, 0, stream>>>(Ab, Wot, bo, out, M_ROWS, E_DIM,
                                             E_DIM);
}